// Round 7
// baseline (387.715 us; speedup 1.0000x reference)
//
#include <hip/hip_runtime.h>

#define N_NODES 100000
#define N_EDGES 3200000
#define D 128

#define K1C    391        // coarse buckets: bucket = dst >> 8 (256 nodes each)
#define CHUNK  6144       // edges per partition block
#define NCHUNK 521        // ceil(N_EDGES / CHUNK)

// ---------------------------------------------------------------------------
// Workspace layout (bytes). Total ~77.3 MB; ws >= 78,000,512 proven round 2.
// ---------------------------------------------------------------------------
static const size_t OFF_SB    = 0;           // S bf16 packed: N*64 uints = 25.6 MB
static const size_t OFF_REC   = 25600000;    // E int2 (coarse-partitioned)
static const size_t OFF_SORT2 = 51200000;    // E int2 (fine-sorted)
static const size_t OFF_OFFS  = 76800000;    // N ints
static const size_t OFF_GHIST = 77200000;
static const size_t OFF_BOFFS = 77204096;
static const size_t OFF_GCUR  = 77208192;

typedef __attribute__((ext_vector_type(8))) short bf16x8;
typedef __attribute__((ext_vector_type(4))) float f32x4;

__device__ __forceinline__ unsigned short f2bf(float f) {
    unsigned u = __float_as_uint(f);
    return (unsigned short)((u + 0x7FFFu + ((u >> 16) & 1u)) >> 16);   // RNE
}

// ---------------------------------------------------------------------------
// S = X @ W via MFMA — verified (absmax matched VALU-bf16 path).
// ---------------------------------------------------------------------------
__global__ __launch_bounds__(256) void gemm_mfma(const float* __restrict__ X,
                                                 const float* __restrict__ W,
                                                 unsigned* __restrict__ Sb) {
    __shared__ __align__(16) union {
        unsigned short wfrag[8][4][64][8];  // [ct][kt][lane][j] = 32 KB
        unsigned       stage[4][32][68];    // [wave][row][dword] = 34 KB
    } u;

    const int t    = threadIdx.x;
    const int lane = t & 63;
    const int wave = t >> 6;
    const int quad = lane >> 4;
    const int li   = lane & 15;
    const int rowBase = blockIdx.x * 128;

    // stage W[k][n] fp32 -> pre-packed bf16 B-fragments
    for (int i = t; i < D * D; i += 256) {
        int k = i >> 7, n = i & 127;
        u.wfrag[n >> 4][k >> 5][((k >> 3) & 3) * 16 + (n & 15)][k & 7] = f2bf(W[i]);
    }
    __syncthreads();

    f32x4 acc[2][8];
#pragma unroll
    for (int rt = 0; rt < 2; ++rt)
#pragma unroll
        for (int ct = 0; ct < 8; ++ct)
            acc[rt][ct] = (f32x4){0.f, 0.f, 0.f, 0.f};

#pragma unroll
    for (int kt = 0; kt < 4; ++kt) {
        bf16x8 a[2];
#pragma unroll
        for (int rt = 0; rt < 2; ++rt) {
            int row = rowBase + wave * 32 + rt * 16 + li;
            if (row >= N_NODES) row = N_NODES - 1;           // clamp; store masked
            const float* xp = X + (size_t)row * D + kt * 32 + quad * 8;
            float4 f0 = ((const float4*)xp)[0];
            float4 f1 = ((const float4*)xp)[1];
            bf16x8 av;
            av[0] = (short)f2bf(f0.x); av[1] = (short)f2bf(f0.y);
            av[2] = (short)f2bf(f0.z); av[3] = (short)f2bf(f0.w);
            av[4] = (short)f2bf(f1.x); av[5] = (short)f2bf(f1.y);
            av[6] = (short)f2bf(f1.z); av[7] = (short)f2bf(f1.w);
            a[rt] = av;
        }
#pragma unroll
        for (int ct = 0; ct < 8; ++ct) {
            bf16x8 b = *(const bf16x8*)&u.wfrag[ct][kt][lane][0];
            acc[0][ct] = __builtin_amdgcn_mfma_f32_16x16x32_bf16(a[0], b, acc[0][ct], 0, 0, 0);
            acc[1][ct] = __builtin_amdgcn_mfma_f32_16x16x32_bf16(a[1], b, acc[1][ct], 0, 0, 0);
        }
    }
    __syncthreads();

    unsigned short* sw = (unsigned short*)&u.stage[wave][0][0];  // 32 x 136 bf16
#pragma unroll
    for (int rt = 0; rt < 2; ++rt)
#pragma unroll
        for (int r = 0; r < 4; ++r) {
            int lrow = rt * 16 + quad * 4 + r;
#pragma unroll
            for (int ct = 0; ct < 8; ++ct)
                sw[lrow * 136 + ct * 16 + li] = f2bf(acc[rt][ct][r]);
        }
    for (int lrow = 0; lrow < 32; ++lrow) {
        int node = rowBase + wave * 32 + lrow;
        if (node < N_NODES)
            Sb[(size_t)node * 64 + lane] = ((unsigned*)sw)[lrow * 68 + lane];
    }
}

// ---------------------------------------------------------------------------
// Coarse histogram over K1C buckets (bucket = dst >> 8)
// ---------------------------------------------------------------------------
__global__ __launch_bounds__(256) void hist_coarse(const int* __restrict__ edst,
                                                   int* __restrict__ ghist) {
    __shared__ int h[K1C];
    for (int i = threadIdx.x; i < K1C; i += 256) h[i] = 0;
    __syncthreads();
    for (int e = blockIdx.x * 256 + threadIdx.x; e < N_EDGES; e += gridDim.x * 256)
        atomicAdd(&h[edst[e] >> 8], 1);
    __syncthreads();
    for (int i = threadIdx.x; i < K1C; i += 256)
        if (h[i]) atomicAdd(&ghist[i], h[i]);
}

__global__ __launch_bounds__(256) void scan_coarse(const int* __restrict__ ghist,
                                                   int* __restrict__ boffs,
                                                   int* __restrict__ gcursor) {
    __shared__ int sc[256];
    const int t = threadIdx.x;
    int v[2]; int s = 0;
#pragma unroll
    for (int j = 0; j < 2; ++j) {
        int idx = t * 2 + j;
        v[j] = (idx < K1C) ? ghist[idx] : 0;
        s += v[j];
    }
    sc[t] = s;
    __syncthreads();
    for (int off = 1; off < 256; off <<= 1) {
        int u = (t >= off) ? sc[t - off] : 0;
        __syncthreads();
        sc[t] += u;
        __syncthreads();
    }
    int run = (t == 0) ? 0 : sc[t - 1];
#pragma unroll
    for (int j = 0; j < 2; ++j) {
        int idx = t * 2 + j;
        if (idx < K1C) { boffs[idx] = run; gcursor[idx] = run; }
        run += v[j];
    }
    if (t == 255) boffs[K1C] = run;
}

// ---------------------------------------------------------------------------
// Scan-free, stage-free coarse partition. Per block: (1) LDS histogram of
// CHUNK edges; (2) one global atomicAdd per nonempty bucket reserves this
// block's output range; (3) re-read edges (L2-hot) and scatter records
// DIRECTLY to global via LDS cursor. Bucket-region writes (25.6 MB total)
// are L2-resident; fragments ~126 B fill lines quickly.
// LDS 3.1 KB (was 68 KB -> 2 blk/CU), 4 barriers (was ~20), 2 sweeps (was 3).
// rec.x = src | (dst&255)<<17 ; rec.y = val bits.  Int atomics only.
// ---------------------------------------------------------------------------
__global__ __launch_bounds__(512) void partition_edges(
        const int* __restrict__ esrc,
        const int* __restrict__ edst,
        const float* __restrict__ eval,
        int* __restrict__ gcursor,
        int2* __restrict__ rec_out) {
    __shared__ int hist[K1C];
    __shared__ int gpos[K1C];

    const int t   = threadIdx.x;
    const int e0  = blockIdx.x * CHUNK;
    const int cnt = min(CHUNK, N_EDGES - e0);

    for (int i = t; i < K1C; i += 512) hist[i] = 0;
    __syncthreads();

    // pass 1: block-local histogram (coalesced edst read)
    for (int i = t; i < cnt; i += 512)
        atomicAdd(&hist[edst[e0 + i] >> 8], 1);
    __syncthreads();

    // reserve contiguous global ranges, one atomic per nonempty bucket
    if (t < K1C) {
        int hv = hist[t];
        gpos[t] = hv ? atomicAdd(&gcursor[t], hv) : 0;
    }
    __syncthreads();

    // pass 2: re-read edges (edst L2-hot), scatter records directly to global
    for (int i = t; i < cnt; i += 512) {
        int e = e0 + i;
        int d = edst[e];
        int b = d >> 8;
        int p = atomicAdd(&gpos[b], 1);
        rec_out[p] = make_int2(esrc[e] | ((d & 255) << 17), __float_as_int(eval[e]));
    }
}

// ---------------------------------------------------------------------------
// Fine sort within each 256-node coarse bucket. 512 threads; scan via
// per-wave __shfl_up + one cross-wave combine (3 barriers, was 14).
// Scatter window ~65 KB -> L2-resident. Emits per-node segment offsets.
// ---------------------------------------------------------------------------
__global__ __launch_bounds__(512) void fine_sort(
        const int2* __restrict__ rec,
        const int* __restrict__ boffs,
        int* __restrict__ offs,
        int2* __restrict__ sorted2) {
    __shared__ int h[256];
    __shared__ int cur[256];
    __shared__ int wsum[4];

    const int c    = blockIdx.x;
    const int t    = threadIdx.x;
    const int lane = t & 63;
    const int wave = t >> 6;
    const int beg  = boffs[c];
    const int end  = boffs[c + 1];

    if (t < 256) h[t] = 0;
    __syncthreads();

    for (int i = beg + t; i < end; i += 512)
        atomicAdd(&h[(rec[i].x >> 17) & 255], 1);
    __syncthreads();

    // inclusive scan of h[0..255]: waves 0-3 handle 64 entries each
    int incl = 0, hv = 0;
    if (t < 256) {
        hv = h[t];
        incl = hv;
        for (int off = 1; off < 64; off <<= 1) {
            int u = __shfl_up(incl, off);
            if (lane >= off) incl += u;
        }
        if (lane == 63) wsum[wave] = incl;
    }
    __syncthreads();
    if (t < 256) {
        int pre = 0;
        for (int w = 0; w < wave; ++w) pre += wsum[w];
        int excl = pre + incl - hv;
        int node = c * 256 + t;
        if (node < N_NODES) offs[node] = beg + excl;
        cur[t] = beg + excl;
    }
    __syncthreads();

    for (int i = beg + t; i < end; i += 512) {
        int2 q = rec[i];
        int dl = (q.x >> 17) & 255;
        int p = atomicAdd(&cur[dl], 1);
        sorted2[p] = make_int2(q.x & 0x1FFFF, q.y);
    }
}

// ---------------------------------------------------------------------------
// Wave-per-node segmented reduce, QUARTER-wave record parallelism (verified
// round 4; bitonic-sort experiment reverted after null FETCH result):
// lane quarter qr = lane>>4 owns record 4g+qr of each group g; 16 lanes per
// quarter each load uint4 (16 B) -> one full 256 B S-row per record per
// instruction. 4 groups unrolled -> 4 outstanding dwordx4 loads = 4 KB in
// flight per wave. Quarters combined via shfl(lane^16)+shfl(lane^32).
// Tail records are zero-padded (val=0, src=0) -> harmless row-0 loads.
// ---------------------------------------------------------------------------
#define FMA8(v, p) {                                                         \
    a0 += (v) * __uint_as_float((p).x << 16);                                \
    a1 += (v) * __uint_as_float((p).x & 0xFFFF0000u);                        \
    a2 += (v) * __uint_as_float((p).y << 16);                                \
    a3 += (v) * __uint_as_float((p).y & 0xFFFF0000u);                        \
    a4 += (v) * __uint_as_float((p).z << 16);                                \
    a5 += (v) * __uint_as_float((p).z & 0xFFFF0000u);                        \
    a6 += (v) * __uint_as_float((p).w << 16);                                \
    a7 += (v) * __uint_as_float((p).w & 0xFFFF0000u);                        \
}

__global__ __launch_bounds__(256) void reduce_segments(
        const unsigned* __restrict__ Sb,
        const int2* __restrict__ sorted,
        const int* __restrict__ offs,
        const float* __restrict__ bias,
        float* __restrict__ out) {
    const int lane = threadIdx.x & 63;
    const int node = (blockIdx.x * 256 + threadIdx.x) >> 6;
    if (node >= N_NODES) return;

    const int qr = lane >> 4;        // which record of the group of 4
    const int ql = lane & 15;        // lane within quarter: feats 8ql..8ql+7

    const int beg = offs[node];
    const int end = (node == N_NODES - 1) ? N_EDGES : offs[node + 1];

    float a0 = 0.f, a1 = 0.f, a2 = 0.f, a3 = 0.f;
    float a4 = 0.f, a5 = 0.f, a6 = 0.f, a7 = 0.f;

    for (int base = beg; base < end; base += 64) {
        const int m = min(64, end - base);
        int2 rec = make_int2(0, 0);
        if (base + lane < end) rec = sorted[base + lane];
        const int ng = (m + 3) >> 2;         // groups of 4 records

        int g = 0;
        for (; g + 4 <= ng; g += 4) {
            int i0 = 4 * (g + 0) + qr, i1 = 4 * (g + 1) + qr;
            int i2 = 4 * (g + 2) + qr, i3 = 4 * (g + 3) + qr;
            int s0 = __shfl(rec.x, i0); int s1 = __shfl(rec.x, i1);
            int s2 = __shfl(rec.x, i2); int s3 = __shfl(rec.x, i3);
            float v0 = __int_as_float(__shfl(rec.y, i0));
            float v1 = __int_as_float(__shfl(rec.y, i1));
            float v2 = __int_as_float(__shfl(rec.y, i2));
            float v3 = __int_as_float(__shfl(rec.y, i3));
            uint4 p0 = ((const uint4*)(Sb + (size_t)s0 * 64))[ql];
            uint4 p1 = ((const uint4*)(Sb + (size_t)s1 * 64))[ql];
            uint4 p2 = ((const uint4*)(Sb + (size_t)s2 * 64))[ql];
            uint4 p3 = ((const uint4*)(Sb + (size_t)s3 * 64))[ql];
            FMA8(v0, p0);
            FMA8(v1, p1);
            FMA8(v2, p2);
            FMA8(v3, p3);
        }
        for (; g < ng; ++g) {
            int i0 = 4 * g + qr;
            int s0 = __shfl(rec.x, i0);
            float v0 = __int_as_float(__shfl(rec.y, i0));
            uint4 p0 = ((const uint4*)(Sb + (size_t)s0 * 64))[ql];
            FMA8(v0, p0);
        }
    }

    // combine the four quarters (feats 8ql..8ql+7 live in lanes ql, ql+16,
    // ql+32, ql+48)
    a0 += __shfl(a0, lane ^ 16); a1 += __shfl(a1, lane ^ 16);
    a2 += __shfl(a2, lane ^ 16); a3 += __shfl(a3, lane ^ 16);
    a4 += __shfl(a4, lane ^ 16); a5 += __shfl(a5, lane ^ 16);
    a6 += __shfl(a6, lane ^ 16); a7 += __shfl(a7, lane ^ 16);
    a0 += __shfl(a0, lane ^ 32); a1 += __shfl(a1, lane ^ 32);
    a2 += __shfl(a2, lane ^ 32); a3 += __shfl(a3, lane ^ 32);
    a4 += __shfl(a4, lane ^ 32); a5 += __shfl(a5, lane ^ 32);
    a6 += __shfl(a6, lane ^ 32); a7 += __shfl(a7, lane ^ 32);

    if (qr == 0) {
        float4 b0 = ((const float4*)bias)[2 * ql];
        float4 b1 = ((const float4*)bias)[2 * ql + 1];
        float4 r0 = make_float4(a0 + b0.x, a1 + b0.y, a2 + b0.z, a3 + b0.w);
        float4 r1 = make_float4(a4 + b1.x, a5 + b1.y, a6 + b1.z, a7 + b1.w);
        ((float4*)(out + (size_t)node * D))[2 * ql]     = r0;
        ((float4*)(out + (size_t)node * D))[2 * ql + 1] = r1;
    }
}

extern "C" void kernel_launch(void* const* d_in, const int* in_sizes, int n_in,
                              void* d_out, int out_size, void* d_ws, size_t ws_size,
                              hipStream_t stream) {
    const float* X    = (const float*)d_in[0];
    const int*   esrc = (const int*)  d_in[1];
    const int*   edst = (const int*)  d_in[2];
    const float* eval = (const float*)d_in[3];
    const float* W    = (const float*)d_in[4];
    const float* bias = (const float*)d_in[5];
    float* out = (float*)d_out;

    char* ws = (char*)d_ws;
    unsigned* SbU   = (unsigned*)(ws + OFF_SB);
    int2*     recs  = (int2*)    (ws + OFF_REC);
    int2*     srt2  = (int2*)    (ws + OFF_SORT2);
    int*      offs  = (int*)     (ws + OFF_OFFS);
    int*      ghist = (int*)     (ws + OFF_GHIST);
    int*      boffs = (int*)     (ws + OFF_BOFFS);
    int*      gcur  = (int*)     (ws + OFF_GCUR);

    // S = X @ W (bf16, MFMA)
    gemm_mfma<<<782, 256, 0, stream>>>(X, W, SbU);

    // Two-level counting sort of edges by dst (all scatters L2-resident)
    hipMemsetAsync(ghist, 0, K1C * 4, stream);
    hist_coarse<<<256, 256, 0, stream>>>(edst, ghist);
    scan_coarse<<<1, 256, 0, stream>>>(ghist, boffs, gcur);
    partition_edges<<<NCHUNK, 512, 0, stream>>>(esrc, edst, eval, gcur, recs);
    fine_sort<<<K1C, 512, 0, stream>>>(recs, boffs, offs, srt2);

    // Segmented reduce: out[n] = bias + sum val * S[src]
    reduce_segments<<<(N_NODES + 3) / 4, 256, 0, stream>>>(
        SbU, srt2, offs, bias, out);
}

// Round 8
// 355.574 us; speedup vs baseline: 1.0904x; 1.0904x over previous
//
#include <hip/hip_runtime.h>

#define N_NODES 100000
#define N_EDGES 3200000
#define D 128

#define K1C    391        // coarse buckets: bucket = dst >> 8 (256 nodes each)
#define CHUNK  4096       // edges per partition block (LDS 47 KB -> 3 blk/CU)
#define NCHUNK 782        // ceil(N_EDGES / CHUNK)

// ---------------------------------------------------------------------------
// Workspace layout (bytes). Total ~77.3 MB; ws >= 78,000,512 proven round 2.
// ---------------------------------------------------------------------------
static const size_t OFF_SB    = 0;           // S bf16 packed: N*64 uints = 25.6 MB
static const size_t OFF_REC   = 25600000;    // E int2 (coarse-partitioned)
static const size_t OFF_SORT2 = 51200000;    // E int2 (fine-sorted)
static const size_t OFF_OFFS  = 76800000;    // N ints
static const size_t OFF_GHIST = 77200000;
static const size_t OFF_BOFFS = 77204096;
static const size_t OFF_GCUR  = 77208192;

typedef __attribute__((ext_vector_type(8))) short bf16x8;
typedef __attribute__((ext_vector_type(4))) float f32x4;

__device__ __forceinline__ unsigned short f2bf(float f) {
    unsigned u = __float_as_uint(f);
    return (unsigned short)((u + 0x7FFFu + ((u >> 16) & 1u)) >> 16);   // RNE
}

// ---------------------------------------------------------------------------
// S = X @ W via MFMA — verified (absmax matched VALU-bf16 path).
// ---------------------------------------------------------------------------
__global__ __launch_bounds__(256) void gemm_mfma(const float* __restrict__ X,
                                                 const float* __restrict__ W,
                                                 unsigned* __restrict__ Sb) {
    __shared__ __align__(16) union {
        unsigned short wfrag[8][4][64][8];  // [ct][kt][lane][j] = 32 KB
        unsigned       stage[4][32][68];    // [wave][row][dword] = 34 KB
    } u;

    const int t    = threadIdx.x;
    const int lane = t & 63;
    const int wave = t >> 6;
    const int quad = lane >> 4;
    const int li   = lane & 15;
    const int rowBase = blockIdx.x * 128;

    // stage W[k][n] fp32 -> pre-packed bf16 B-fragments
    for (int i = t; i < D * D; i += 256) {
        int k = i >> 7, n = i & 127;
        u.wfrag[n >> 4][k >> 5][((k >> 3) & 3) * 16 + (n & 15)][k & 7] = f2bf(W[i]);
    }
    __syncthreads();

    f32x4 acc[2][8];
#pragma unroll
    for (int rt = 0; rt < 2; ++rt)
#pragma unroll
        for (int ct = 0; ct < 8; ++ct)
            acc[rt][ct] = (f32x4){0.f, 0.f, 0.f, 0.f};

#pragma unroll
    for (int kt = 0; kt < 4; ++kt) {
        bf16x8 a[2];
#pragma unroll
        for (int rt = 0; rt < 2; ++rt) {
            int row = rowBase + wave * 32 + rt * 16 + li;
            if (row >= N_NODES) row = N_NODES - 1;           // clamp; store masked
            const float* xp = X + (size_t)row * D + kt * 32 + quad * 8;
            float4 f0 = ((const float4*)xp)[0];
            float4 f1 = ((const float4*)xp)[1];
            bf16x8 av;
            av[0] = (short)f2bf(f0.x); av[1] = (short)f2bf(f0.y);
            av[2] = (short)f2bf(f0.z); av[3] = (short)f2bf(f0.w);
            av[4] = (short)f2bf(f1.x); av[5] = (short)f2bf(f1.y);
            av[6] = (short)f2bf(f1.z); av[7] = (short)f2bf(f1.w);
            a[rt] = av;
        }
#pragma unroll
        for (int ct = 0; ct < 8; ++ct) {
            bf16x8 b = *(const bf16x8*)&u.wfrag[ct][kt][lane][0];
            acc[0][ct] = __builtin_amdgcn_mfma_f32_16x16x32_bf16(a[0], b, acc[0][ct], 0, 0, 0);
            acc[1][ct] = __builtin_amdgcn_mfma_f32_16x16x32_bf16(a[1], b, acc[1][ct], 0, 0, 0);
        }
    }
    __syncthreads();

    unsigned short* sw = (unsigned short*)&u.stage[wave][0][0];  // 32 x 136 bf16
#pragma unroll
    for (int rt = 0; rt < 2; ++rt)
#pragma unroll
        for (int r = 0; r < 4; ++r) {
            int lrow = rt * 16 + quad * 4 + r;
#pragma unroll
            for (int ct = 0; ct < 8; ++ct)
                sw[lrow * 136 + ct * 16 + li] = f2bf(acc[rt][ct][r]);
        }
    for (int lrow = 0; lrow < 32; ++lrow) {
        int node = rowBase + wave * 32 + lrow;
        if (node < N_NODES)
            Sb[(size_t)node * 64 + lane] = ((unsigned*)sw)[lrow * 68 + lane];
    }
}

// ---------------------------------------------------------------------------
// Coarse histogram over K1C buckets (bucket = dst >> 8)
// ---------------------------------------------------------------------------
__global__ __launch_bounds__(256) void hist_coarse(const int* __restrict__ edst,
                                                   int* __restrict__ ghist) {
    __shared__ int h[K1C];
    for (int i = threadIdx.x; i < K1C; i += 256) h[i] = 0;
    __syncthreads();
    for (int e = blockIdx.x * 256 + threadIdx.x; e < N_EDGES; e += gridDim.x * 256)
        atomicAdd(&h[edst[e] >> 8], 1);
    __syncthreads();
    for (int i = threadIdx.x; i < K1C; i += 256)
        if (h[i]) atomicAdd(&ghist[i], h[i]);
}

__global__ __launch_bounds__(256) void scan_coarse(const int* __restrict__ ghist,
                                                   int* __restrict__ boffs,
                                                   int* __restrict__ gcursor) {
    __shared__ int sc[256];
    const int t = threadIdx.x;
    int v[2]; int s = 0;
#pragma unroll
    for (int j = 0; j < 2; ++j) {
        int idx = t * 2 + j;
        v[j] = (idx < K1C) ? ghist[idx] : 0;
        s += v[j];
    }
    sc[t] = s;
    __syncthreads();
    for (int off = 1; off < 256; off <<= 1) {
        int u = (t >= off) ? sc[t - off] : 0;
        __syncthreads();
        sc[t] += u;
        __syncthreads();
    }
    int run = (t == 0) ? 0 : sc[t - 1];
#pragma unroll
    for (int j = 0; j < 2; ++j) {
        int idx = t * 2 + j;
        if (idx < K1C) { boffs[idx] = run; gcursor[idx] = run; }
        run += v[j];
    }
    if (t == 255) boffs[K1C] = run;
}

// ---------------------------------------------------------------------------
// LDS-staged coarse partition, two-pass-per-block (hist then re-read+scatter),
// restored from the verified R1/R4 form with two occupancy fixes:
//   - CHUNK 4096: staged+bkt = 40 KB, total LDS ~47 KB -> 3 blocks/CU (75%)
//   - wave __shfl_up scan + cross-wave combine (3 barriers, was 18)
// Writeout stays LDS-staged (direct global scatter proven -25 us in R7).
// rec.x = src | (dst&255)<<17 ; rec.y = val bits.  Int atomics only.
// ---------------------------------------------------------------------------
__global__ __launch_bounds__(512) void partition_edges(
        const int* __restrict__ esrc,
        const int* __restrict__ edst,
        const float* __restrict__ eval,
        int* __restrict__ gcursor,
        int2* __restrict__ rec_out) {
    __shared__ int  hist[K1C];
    __shared__ int  lofs[K1C];
    __shared__ int  gbase[K1C];
    __shared__ int  cur[K1C];
    __shared__ int  wsum[8];
    __shared__ int2 staged[CHUNK];
    __shared__ unsigned short bkt[CHUNK];

    const int t    = threadIdx.x;
    const int lane = t & 63;
    const int wave = t >> 6;
    const int e0   = blockIdx.x * CHUNK;
    const int cnt  = min(CHUNK, N_EDGES - e0);

    for (int i = t; i < K1C; i += 512) hist[i] = 0;
    __syncthreads();

    // pass 1: block-local histogram (coalesced edst read; re-read is L2-hot)
    for (int i = t; i < cnt; i += 512)
        atomicAdd(&hist[edst[e0 + i] >> 8], 1);
    __syncthreads();

    // scan K1C entries: per-wave shfl_up inclusive scan + cross-wave combine
    int hv   = (t < K1C) ? hist[t] : 0;
    int incl = hv;
    for (int off = 1; off < 64; off <<= 1) {
        int u = __shfl_up(incl, off);
        if (lane >= off) incl += u;
    }
    if (lane == 63) wsum[wave] = incl;
    __syncthreads();
    {
        int pre = 0;
        for (int w = 0; w < wave; ++w) pre += wsum[w];
        if (t < K1C) {
            int excl = pre + incl - hv;
            lofs[t]  = excl;
            cur[t]   = excl;
            gbase[t] = hv ? atomicAdd(&gcursor[t], hv) : 0;
        }
    }
    __syncthreads();

    // pass 2: re-read edges, scatter into LDS staging (bucket-sorted)
    for (int i = t; i < cnt; i += 512) {
        int e = e0 + i;
        int d = edst[e];
        int b = d >> 8;
        int pos = atomicAdd(&cur[b], 1);
        staged[pos] = make_int2(esrc[e] | ((d & 255) << 17), __float_as_int(eval[e]));
        bkt[pos] = (unsigned short)b;
    }
    __syncthreads();

    // writeout: contiguous per-bucket runs (~84 B each), coalesced from LDS
    for (int i = t; i < cnt; i += 512) {
        int bb = bkt[i];
        rec_out[gbase[bb] + (i - lofs[bb])] = staged[i];
    }
}

// ---------------------------------------------------------------------------
// Fine sort within each 256-node coarse bucket. 512 threads; scan via
// per-wave __shfl_up + one cross-wave combine (3 barriers).
// Scatter window ~65 KB -> L2-resident. Emits per-node segment offsets.
// ---------------------------------------------------------------------------
__global__ __launch_bounds__(512) void fine_sort(
        const int2* __restrict__ rec,
        const int* __restrict__ boffs,
        int* __restrict__ offs,
        int2* __restrict__ sorted2) {
    __shared__ int h[256];
    __shared__ int cur[256];
    __shared__ int wsum[4];

    const int c    = blockIdx.x;
    const int t    = threadIdx.x;
    const int lane = t & 63;
    const int wave = t >> 6;
    const int beg  = boffs[c];
    const int end  = boffs[c + 1];

    if (t < 256) h[t] = 0;
    __syncthreads();

    for (int i = beg + t; i < end; i += 512)
        atomicAdd(&h[(rec[i].x >> 17) & 255], 1);
    __syncthreads();

    // inclusive scan of h[0..255]: waves 0-3 handle 64 entries each
    int incl = 0, hv = 0;
    if (t < 256) {
        hv = h[t];
        incl = hv;
        for (int off = 1; off < 64; off <<= 1) {
            int u = __shfl_up(incl, off);
            if (lane >= off) incl += u;
        }
        if (lane == 63) wsum[wave] = incl;
    }
    __syncthreads();
    if (t < 256) {
        int pre = 0;
        for (int w = 0; w < wave; ++w) pre += wsum[w];
        int excl = pre + incl - hv;
        int node = c * 256 + t;
        if (node < N_NODES) offs[node] = beg + excl;
        cur[t] = beg + excl;
    }
    __syncthreads();

    for (int i = beg + t; i < end; i += 512) {
        int2 q = rec[i];
        int dl = (q.x >> 17) & 255;
        int p = atomicAdd(&cur[dl], 1);
        sorted2[p] = make_int2(q.x & 0x1FFFF, q.y);
    }
}

// ---------------------------------------------------------------------------
// Wave-per-node segmented reduce, QUARTER-wave record parallelism (verified
// round 4; at its measured floor: FETCH ~358 MB regardless of MLP/order):
// lane quarter qr = lane>>4 owns record 4g+qr of each group g; 16 lanes per
// quarter each load uint4 (16 B) -> one full 256 B S-row per record per
// instruction. 4 groups unrolled -> 4 outstanding dwordx4 loads = 4 KB in
// flight per wave. Quarters combined via shfl(lane^16)+shfl(lane^32).
// Tail records are zero-padded (val=0, src=0) -> harmless row-0 loads.
// ---------------------------------------------------------------------------
#define FMA8(v, p) {                                                         \
    a0 += (v) * __uint_as_float((p).x << 16);                                \
    a1 += (v) * __uint_as_float((p).x & 0xFFFF0000u);                        \
    a2 += (v) * __uint_as_float((p).y << 16);                                \
    a3 += (v) * __uint_as_float((p).y & 0xFFFF0000u);                        \
    a4 += (v) * __uint_as_float((p).z << 16);                                \
    a5 += (v) * __uint_as_float((p).z & 0xFFFF0000u);                        \
    a6 += (v) * __uint_as_float((p).w << 16);                                \
    a7 += (v) * __uint_as_float((p).w & 0xFFFF0000u);                        \
}

__global__ __launch_bounds__(256) void reduce_segments(
        const unsigned* __restrict__ Sb,
        const int2* __restrict__ sorted,
        const int* __restrict__ offs,
        const float* __restrict__ bias,
        float* __restrict__ out) {
    const int lane = threadIdx.x & 63;
    const int node = (blockIdx.x * 256 + threadIdx.x) >> 6;
    if (node >= N_NODES) return;

    const int qr = lane >> 4;        // which record of the group of 4
    const int ql = lane & 15;        // lane within quarter: feats 8ql..8ql+7

    const int beg = offs[node];
    const int end = (node == N_NODES - 1) ? N_EDGES : offs[node + 1];

    float a0 = 0.f, a1 = 0.f, a2 = 0.f, a3 = 0.f;
    float a4 = 0.f, a5 = 0.f, a6 = 0.f, a7 = 0.f;

    for (int base = beg; base < end; base += 64) {
        const int m = min(64, end - base);
        int2 rec = make_int2(0, 0);
        if (base + lane < end) rec = sorted[base + lane];
        const int ng = (m + 3) >> 2;         // groups of 4 records

        int g = 0;
        for (; g + 4 <= ng; g += 4) {
            int i0 = 4 * (g + 0) + qr, i1 = 4 * (g + 1) + qr;
            int i2 = 4 * (g + 2) + qr, i3 = 4 * (g + 3) + qr;
            int s0 = __shfl(rec.x, i0); int s1 = __shfl(rec.x, i1);
            int s2 = __shfl(rec.x, i2); int s3 = __shfl(rec.x, i3);
            float v0 = __int_as_float(__shfl(rec.y, i0));
            float v1 = __int_as_float(__shfl(rec.y, i1));
            float v2 = __int_as_float(__shfl(rec.y, i2));
            float v3 = __int_as_float(__shfl(rec.y, i3));
            uint4 p0 = ((const uint4*)(Sb + (size_t)s0 * 64))[ql];
            uint4 p1 = ((const uint4*)(Sb + (size_t)s1 * 64))[ql];
            uint4 p2 = ((const uint4*)(Sb + (size_t)s2 * 64))[ql];
            uint4 p3 = ((const uint4*)(Sb + (size_t)s3 * 64))[ql];
            FMA8(v0, p0);
            FMA8(v1, p1);
            FMA8(v2, p2);
            FMA8(v3, p3);
        }
        for (; g < ng; ++g) {
            int i0 = 4 * g + qr;
            int s0 = __shfl(rec.x, i0);
            float v0 = __int_as_float(__shfl(rec.y, i0));
            uint4 p0 = ((const uint4*)(Sb + (size_t)s0 * 64))[ql];
            FMA8(v0, p0);
        }
    }

    // combine the four quarters (feats 8ql..8ql+7 live in lanes ql, ql+16,
    // ql+32, ql+48)
    a0 += __shfl(a0, lane ^ 16); a1 += __shfl(a1, lane ^ 16);
    a2 += __shfl(a2, lane ^ 16); a3 += __shfl(a3, lane ^ 16);
    a4 += __shfl(a4, lane ^ 16); a5 += __shfl(a5, lane ^ 16);
    a6 += __shfl(a6, lane ^ 16); a7 += __shfl(a7, lane ^ 16);
    a0 += __shfl(a0, lane ^ 32); a1 += __shfl(a1, lane ^ 32);
    a2 += __shfl(a2, lane ^ 32); a3 += __shfl(a3, lane ^ 32);
    a4 += __shfl(a4, lane ^ 32); a5 += __shfl(a5, lane ^ 32);
    a6 += __shfl(a6, lane ^ 32); a7 += __shfl(a7, lane ^ 32);

    if (qr == 0) {
        float4 b0 = ((const float4*)bias)[2 * ql];
        float4 b1 = ((const float4*)bias)[2 * ql + 1];
        float4 r0 = make_float4(a0 + b0.x, a1 + b0.y, a2 + b0.z, a3 + b0.w);
        float4 r1 = make_float4(a4 + b1.x, a5 + b1.y, a6 + b1.z, a7 + b1.w);
        ((float4*)(out + (size_t)node * D))[2 * ql]     = r0;
        ((float4*)(out + (size_t)node * D))[2 * ql + 1] = r1;
    }
}

extern "C" void kernel_launch(void* const* d_in, const int* in_sizes, int n_in,
                              void* d_out, int out_size, void* d_ws, size_t ws_size,
                              hipStream_t stream) {
    const float* X    = (const float*)d_in[0];
    const int*   esrc = (const int*)  d_in[1];
    const int*   edst = (const int*)  d_in[2];
    const float* eval = (const float*)d_in[3];
    const float* W    = (const float*)d_in[4];
    const float* bias = (const float*)d_in[5];
    float* out = (float*)d_out;

    char* ws = (char*)d_ws;
    unsigned* SbU   = (unsigned*)(ws + OFF_SB);
    int2*     recs  = (int2*)    (ws + OFF_REC);
    int2*     srt2  = (int2*)    (ws + OFF_SORT2);
    int*      offs  = (int*)     (ws + OFF_OFFS);
    int*      ghist = (int*)     (ws + OFF_GHIST);
    int*      boffs = (int*)     (ws + OFF_BOFFS);
    int*      gcur  = (int*)     (ws + OFF_GCUR);

    // S = X @ W (bf16, MFMA)
    gemm_mfma<<<782, 256, 0, stream>>>(X, W, SbU);

    // Two-level counting sort of edges by dst (all scatters L2-resident)
    hipMemsetAsync(ghist, 0, K1C * 4, stream);
    hist_coarse<<<256, 256, 0, stream>>>(edst, ghist);
    scan_coarse<<<1, 256, 0, stream>>>(ghist, boffs, gcur);
    partition_edges<<<NCHUNK, 512, 0, stream>>>(esrc, edst, eval, gcur, recs);
    fine_sort<<<K1C, 512, 0, stream>>>(recs, boffs, offs, srt2);

    // Segmented reduce: out[n] = bias + sum val * S[src]
    reduce_segments<<<(N_NODES + 3) / 4, 256, 0, stream>>>(
        SbU, srt2, offs, bias, out);
}

// Round 9
// 340.742 us; speedup vs baseline: 1.1379x; 1.0435x over previous
//
#include <hip/hip_runtime.h>

#define N_NODES 100000
#define N_EDGES 3200000
#define D 128

#define K1C    391        // coarse buckets: bucket = dst >> 8 (256 nodes each)
#define CHUNK  4096       // edges per partition block (LDS 47 KB -> 3 blk/CU)
#define NCHUNK 782        // ceil(N_EDGES / CHUNK)
#define GEMMB  782        // gemm tiles (128 rows each) in the fused kernel

// ---------------------------------------------------------------------------
// Workspace layout (bytes). Total ~77.3 MB; ws >= 78,000,512 proven round 2.
// SORT2 region now holds packed uint records (12.8 MB used of 25.6).
// ---------------------------------------------------------------------------
static const size_t OFF_SB    = 0;           // S bf16 packed: N*64 uints = 25.6 MB
static const size_t OFF_REC   = 25600000;    // E int2 (coarse-partitioned)
static const size_t OFF_SORT2 = 51200000;    // E uint (fine-sorted, packed)
static const size_t OFF_OFFS  = 76800000;    // N ints
static const size_t OFF_GHIST = 77200000;
static const size_t OFF_BOFFS = 77204096;
static const size_t OFF_GCUR  = 77208192;

typedef __attribute__((ext_vector_type(8))) short bf16x8;
typedef __attribute__((ext_vector_type(4))) float f32x4;

__device__ __forceinline__ unsigned short f2bf(float f) {
    unsigned u = __float_as_uint(f);
    return (unsigned short)((u + 0x7FFFu + ((u >> 16) & 1u)) >> 16);   // RNE
}

// ---------------------------------------------------------------------------
// Coarse histogram over K1C buckets (bucket = dst >> 8)
// ---------------------------------------------------------------------------
__global__ __launch_bounds__(256) void hist_coarse(const int* __restrict__ edst,
                                                   int* __restrict__ ghist) {
    __shared__ int h[K1C];
    for (int i = threadIdx.x; i < K1C; i += 256) h[i] = 0;
    __syncthreads();
    for (int e = blockIdx.x * 256 + threadIdx.x; e < N_EDGES; e += gridDim.x * 256)
        atomicAdd(&h[edst[e] >> 8], 1);
    __syncthreads();
    for (int i = threadIdx.x; i < K1C; i += 256)
        if (h[i]) atomicAdd(&ghist[i], h[i]);
}

__global__ __launch_bounds__(256) void scan_coarse(const int* __restrict__ ghist,
                                                   int* __restrict__ boffs,
                                                   int* __restrict__ gcursor) {
    __shared__ int sc[256];
    const int t = threadIdx.x;
    int v[2]; int s = 0;
#pragma unroll
    for (int j = 0; j < 2; ++j) {
        int idx = t * 2 + j;
        v[j] = (idx < K1C) ? ghist[idx] : 0;
        s += v[j];
    }
    sc[t] = s;
    __syncthreads();
    for (int off = 1; off < 256; off <<= 1) {
        int u = (t >= off) ? sc[t - off] : 0;
        __syncthreads();
        sc[t] += u;
        __syncthreads();
    }
    int run = (t == 0) ? 0 : sc[t - 1];
#pragma unroll
    for (int j = 0; j < 2; ++j) {
        int idx = t * 2 + j;
        if (idx < K1C) { boffs[idx] = run; gcursor[idx] = run; }
        run += v[j];
    }
    if (t == 255) boffs[K1C] = run;
}

// ---------------------------------------------------------------------------
// LDS-staged coarse partition (verified R8): two-pass, shfl-scan, 3 blk/CU.
// rec.x = src | (dst&255)<<17 ; rec.y = val bits.  Int atomics only.
// ---------------------------------------------------------------------------
__global__ __launch_bounds__(512) void partition_edges(
        const int* __restrict__ esrc,
        const int* __restrict__ edst,
        const float* __restrict__ eval,
        int* __restrict__ gcursor,
        int2* __restrict__ rec_out) {
    __shared__ int  hist[K1C];
    __shared__ int  lofs[K1C];
    __shared__ int  gbase[K1C];
    __shared__ int  cur[K1C];
    __shared__ int  wsum[8];
    __shared__ int2 staged[CHUNK];
    __shared__ unsigned short bkt[CHUNK];

    const int t    = threadIdx.x;
    const int lane = t & 63;
    const int wave = t >> 6;
    const int e0   = blockIdx.x * CHUNK;
    const int cnt  = min(CHUNK, N_EDGES - e0);

    for (int i = t; i < K1C; i += 512) hist[i] = 0;
    __syncthreads();

    // pass 1: block-local histogram (coalesced edst read; re-read is L2-hot)
    for (int i = t; i < cnt; i += 512)
        atomicAdd(&hist[edst[e0 + i] >> 8], 1);
    __syncthreads();

    // scan K1C entries: per-wave shfl_up inclusive scan + cross-wave combine
    int hv   = (t < K1C) ? hist[t] : 0;
    int incl = hv;
    for (int off = 1; off < 64; off <<= 1) {
        int u = __shfl_up(incl, off);
        if (lane >= off) incl += u;
    }
    if (lane == 63) wsum[wave] = incl;
    __syncthreads();
    {
        int pre = 0;
        for (int w = 0; w < wave; ++w) pre += wsum[w];
        if (t < K1C) {
            int excl = pre + incl - hv;
            lofs[t]  = excl;
            cur[t]   = excl;
            gbase[t] = hv ? atomicAdd(&gcursor[t], hv) : 0;
        }
    }
    __syncthreads();

    // pass 2: re-read edges, scatter into LDS staging (bucket-sorted)
    for (int i = t; i < cnt; i += 512) {
        int e = e0 + i;
        int d = edst[e];
        int b = d >> 8;
        int pos = atomicAdd(&cur[b], 1);
        staged[pos] = make_int2(esrc[e] | ((d & 255) << 17), __float_as_int(eval[e]));
        bkt[pos] = (unsigned short)b;
    }
    __syncthreads();

    // writeout: contiguous per-bucket runs (~84 B each), coalesced from LDS
    for (int i = t; i < cnt; i += 512) {
        int bb = bkt[i];
        rec_out[gbase[bb] + (i - lofs[bb])] = staged[i];
    }
}

// ---------------------------------------------------------------------------
// FUSED kernel: blocks [0,GEMMB) run the verified MFMA gemm (S = X@W, 128-row
// tiles, code verbatim from R8); blocks [GEMMB, GEMMB+K1C) run fine_sort
// (256-thread port, wave-shfl scan). The two are data-independent — fusing
// them into one dispatch lets gemm's MFMA waves overlap fine_sort's
// LDS-atomic/memory waves on the same CUs (single-stream HIP never overlaps
// separate kernels). fine_sort emits PACKED records: src(17b)|val-bf16(15b)
// (val>=0 -> sign bit free) — halves record traffic, 1 shfl/record in reduce.
// ---------------------------------------------------------------------------
__global__ __launch_bounds__(256) void gemm_and_fine(
        const float* __restrict__ X,
        const float* __restrict__ W,
        unsigned* __restrict__ Sb,
        const int2* __restrict__ rec,
        const int* __restrict__ boffs,
        int* __restrict__ offs,
        unsigned* __restrict__ sorted1) {
    __shared__ __align__(16) union {
        unsigned short wfrag[8][4][64][8];  // [ct][kt][lane][j] = 32 KB
        unsigned       stage[4][32][68];    // [wave][row][dword] = 34 KB
    } u;
    __shared__ int fh[256];
    __shared__ int fcur[256];
    __shared__ int fwsum[4];

    const int t    = threadIdx.x;
    const int lane = t & 63;
    const int wave = t >> 6;

    if (blockIdx.x < GEMMB) {
        // ----------------- gemm branch (verbatim R8 logic) -----------------
        const int quad = lane >> 4;
        const int li   = lane & 15;
        const int rowBase = blockIdx.x * 128;

        for (int i = t; i < D * D; i += 256) {
            int k = i >> 7, n = i & 127;
            u.wfrag[n >> 4][k >> 5][((k >> 3) & 3) * 16 + (n & 15)][k & 7] = f2bf(W[i]);
        }
        __syncthreads();

        f32x4 acc[2][8];
#pragma unroll
        for (int rt = 0; rt < 2; ++rt)
#pragma unroll
            for (int ct = 0; ct < 8; ++ct)
                acc[rt][ct] = (f32x4){0.f, 0.f, 0.f, 0.f};

#pragma unroll
        for (int kt = 0; kt < 4; ++kt) {
            bf16x8 a[2];
#pragma unroll
            for (int rt = 0; rt < 2; ++rt) {
                int row = rowBase + wave * 32 + rt * 16 + li;
                if (row >= N_NODES) row = N_NODES - 1;       // clamp; store masked
                const float* xp = X + (size_t)row * D + kt * 32 + quad * 8;
                float4 f0 = ((const float4*)xp)[0];
                float4 f1 = ((const float4*)xp)[1];
                bf16x8 av;
                av[0] = (short)f2bf(f0.x); av[1] = (short)f2bf(f0.y);
                av[2] = (short)f2bf(f0.z); av[3] = (short)f2bf(f0.w);
                av[4] = (short)f2bf(f1.x); av[5] = (short)f2bf(f1.y);
                av[6] = (short)f2bf(f1.z); av[7] = (short)f2bf(f1.w);
                a[rt] = av;
            }
#pragma unroll
            for (int ct = 0; ct < 8; ++ct) {
                bf16x8 b = *(const bf16x8*)&u.wfrag[ct][kt][lane][0];
                acc[0][ct] = __builtin_amdgcn_mfma_f32_16x16x32_bf16(a[0], b, acc[0][ct], 0, 0, 0);
                acc[1][ct] = __builtin_amdgcn_mfma_f32_16x16x32_bf16(a[1], b, acc[1][ct], 0, 0, 0);
            }
        }
        __syncthreads();

        unsigned short* sw = (unsigned short*)&u.stage[wave][0][0];  // 32 x 136 bf16
#pragma unroll
        for (int rt = 0; rt < 2; ++rt)
#pragma unroll
            for (int r = 0; r < 4; ++r) {
                int lrow = rt * 16 + quad * 4 + r;
#pragma unroll
                for (int ct = 0; ct < 8; ++ct)
                    sw[lrow * 136 + ct * 16 + li] = f2bf(acc[rt][ct][r]);
            }
        for (int lrow = 0; lrow < 32; ++lrow) {
            int node = rowBase + wave * 32 + lrow;
            if (node < N_NODES)
                Sb[(size_t)node * 64 + lane] = ((unsigned*)sw)[lrow * 68 + lane];
        }
    } else {
        // ----------------- fine_sort branch (256 threads) ------------------
        const int c   = blockIdx.x - GEMMB;
        const int beg = boffs[c];
        const int end = boffs[c + 1];

        fh[t] = 0;
        __syncthreads();

        for (int i = beg + t; i < end; i += 256)
            atomicAdd(&fh[(rec[i].x >> 17) & 255], 1);
        __syncthreads();

        // inclusive scan of fh[0..255]: 4 waves x 64 entries + combine
        int hv   = fh[t];
        int incl = hv;
        for (int off = 1; off < 64; off <<= 1) {
            int uu = __shfl_up(incl, off);
            if (lane >= off) incl += uu;
        }
        if (lane == 63) fwsum[wave] = incl;
        __syncthreads();
        {
            int pre = 0;
            for (int w = 0; w < wave; ++w) pre += fwsum[w];
            int excl = pre + incl - hv;
            int node = c * 256 + t;
            if (node < N_NODES) offs[node] = beg + excl;
            fcur[t] = beg + excl;
        }
        __syncthreads();

        for (int i = beg + t; i < end; i += 256) {
            int2 q = rec[i];
            int dl = (q.x >> 17) & 255;
            int p = atomicAdd(&fcur[dl], 1);
            unsigned vb = f2bf(__int_as_float(q.y));          // val >= 0 -> bit15==0
            sorted1[p] = (unsigned)(q.x & 0x1FFFF) | ((vb & 0x7FFFu) << 17);
        }
    }
}

// ---------------------------------------------------------------------------
// Wave-per-node segmented reduce, QUARTER-wave record parallelism (verified
// R4; at its measured floor: FETCH ~358 MB regardless of MLP/order). Records
// are 4 B packed: src = p & 0x1FFFF, val = bits (p>>17)<<16. One shfl per
// record. 16 lanes per quarter load uint4 -> one 256 B S-row per record.
// Tail records are zero-padded (p=0 -> src 0, val +0.0) -> harmless.
// ---------------------------------------------------------------------------
#define FMA8(v, p) {                                                         \
    a0 += (v) * __uint_as_float((p).x << 16);                                \
    a1 += (v) * __uint_as_float((p).x & 0xFFFF0000u);                        \
    a2 += (v) * __uint_as_float((p).y << 16);                                \
    a3 += (v) * __uint_as_float((p).y & 0xFFFF0000u);                        \
    a4 += (v) * __uint_as_float((p).z << 16);                                \
    a5 += (v) * __uint_as_float((p).z & 0xFFFF0000u);                        \
    a6 += (v) * __uint_as_float((p).w << 16);                                \
    a7 += (v) * __uint_as_float((p).w & 0xFFFF0000u);                        \
}

__global__ __launch_bounds__(256) void reduce_segments(
        const unsigned* __restrict__ Sb,
        const unsigned* __restrict__ sorted,
        const int* __restrict__ offs,
        const float* __restrict__ bias,
        float* __restrict__ out) {
    const int lane = threadIdx.x & 63;
    const int node = (blockIdx.x * 256 + threadIdx.x) >> 6;
    if (node >= N_NODES) return;

    const int qr = lane >> 4;        // which record of the group of 4
    const int ql = lane & 15;        // lane within quarter: feats 8ql..8ql+7

    const int beg = offs[node];
    const int end = (node == N_NODES - 1) ? N_EDGES : offs[node + 1];

    float a0 = 0.f, a1 = 0.f, a2 = 0.f, a3 = 0.f;
    float a4 = 0.f, a5 = 0.f, a6 = 0.f, a7 = 0.f;

    for (int base = beg; base < end; base += 64) {
        const int m = min(64, end - base);
        unsigned rec = 0;
        if (base + lane < end) rec = sorted[base + lane];
        const int ng = (m + 3) >> 2;         // groups of 4 records

        int g = 0;
        for (; g + 4 <= ng; g += 4) {
            int i0 = 4 * (g + 0) + qr, i1 = 4 * (g + 1) + qr;
            int i2 = 4 * (g + 2) + qr, i3 = 4 * (g + 3) + qr;
            unsigned r0 = (unsigned)__shfl((int)rec, i0);
            unsigned r1 = (unsigned)__shfl((int)rec, i1);
            unsigned r2 = (unsigned)__shfl((int)rec, i2);
            unsigned r3 = (unsigned)__shfl((int)rec, i3);
            int s0 = r0 & 0x1FFFF, s1 = r1 & 0x1FFFF;
            int s2 = r2 & 0x1FFFF, s3 = r3 & 0x1FFFF;
            float v0 = __uint_as_float((r0 >> 17) << 16);
            float v1 = __uint_as_float((r1 >> 17) << 16);
            float v2 = __uint_as_float((r2 >> 17) << 16);
            float v3 = __uint_as_float((r3 >> 17) << 16);
            uint4 p0 = ((const uint4*)(Sb + (size_t)s0 * 64))[ql];
            uint4 p1 = ((const uint4*)(Sb + (size_t)s1 * 64))[ql];
            uint4 p2 = ((const uint4*)(Sb + (size_t)s2 * 64))[ql];
            uint4 p3 = ((const uint4*)(Sb + (size_t)s3 * 64))[ql];
            FMA8(v0, p0);
            FMA8(v1, p1);
            FMA8(v2, p2);
            FMA8(v3, p3);
        }
        for (; g < ng; ++g) {
            int i0 = 4 * g + qr;
            unsigned r0 = (unsigned)__shfl((int)rec, i0);
            int s0 = r0 & 0x1FFFF;
            float v0 = __uint_as_float((r0 >> 17) << 16);
            uint4 p0 = ((const uint4*)(Sb + (size_t)s0 * 64))[ql];
            FMA8(v0, p0);
        }
    }

    // combine the four quarters (feats 8ql..8ql+7 live in lanes ql, ql+16,
    // ql+32, ql+48)
    a0 += __shfl(a0, lane ^ 16); a1 += __shfl(a1, lane ^ 16);
    a2 += __shfl(a2, lane ^ 16); a3 += __shfl(a3, lane ^ 16);
    a4 += __shfl(a4, lane ^ 16); a5 += __shfl(a5, lane ^ 16);
    a6 += __shfl(a6, lane ^ 16); a7 += __shfl(a7, lane ^ 16);
    a0 += __shfl(a0, lane ^ 32); a1 += __shfl(a1, lane ^ 32);
    a2 += __shfl(a2, lane ^ 32); a3 += __shfl(a3, lane ^ 32);
    a4 += __shfl(a4, lane ^ 32); a5 += __shfl(a5, lane ^ 32);
    a6 += __shfl(a6, lane ^ 32); a7 += __shfl(a7, lane ^ 32);

    if (qr == 0) {
        float4 b0 = ((const float4*)bias)[2 * ql];
        float4 b1 = ((const float4*)bias)[2 * ql + 1];
        float4 r0 = make_float4(a0 + b0.x, a1 + b0.y, a2 + b0.z, a3 + b0.w);
        float4 r1 = make_float4(a4 + b1.x, a5 + b1.y, a6 + b1.z, a7 + b1.w);
        ((float4*)(out + (size_t)node * D))[2 * ql]     = r0;
        ((float4*)(out + (size_t)node * D))[2 * ql + 1] = r1;
    }
}

extern "C" void kernel_launch(void* const* d_in, const int* in_sizes, int n_in,
                              void* d_out, int out_size, void* d_ws, size_t ws_size,
                              hipStream_t stream) {
    const float* X    = (const float*)d_in[0];
    const int*   esrc = (const int*)  d_in[1];
    const int*   edst = (const int*)  d_in[2];
    const float* eval = (const float*)d_in[3];
    const float* W    = (const float*)d_in[4];
    const float* bias = (const float*)d_in[5];
    float* out = (float*)d_out;

    char* ws = (char*)d_ws;
    unsigned* SbU   = (unsigned*)(ws + OFF_SB);
    int2*     recs  = (int2*)    (ws + OFF_REC);
    unsigned* srt1  = (unsigned*)(ws + OFF_SORT2);
    int*      offs  = (int*)     (ws + OFF_OFFS);
    int*      ghist = (int*)     (ws + OFF_GHIST);
    int*      boffs = (int*)     (ws + OFF_BOFFS);
    int*      gcur  = (int*)     (ws + OFF_GCUR);

    // Edge sort chain (gemm deferred into the fused launch below)
    hipMemsetAsync(ghist, 0, K1C * 4, stream);
    hist_coarse<<<256, 256, 0, stream>>>(edst, ghist);
    scan_coarse<<<1, 256, 0, stream>>>(ghist, boffs, gcur);
    partition_edges<<<NCHUNK, 512, 0, stream>>>(esrc, edst, eval, gcur, recs);

    // Fused: gemm (blocks 0..781) || fine_sort (blocks 782..1172)
    gemm_and_fine<<<GEMMB + K1C, 256, 0, stream>>>(
        X, W, SbU, recs, boffs, offs, srt1);

    // Segmented reduce: out[n] = bias + sum val * S[src]
    reduce_segments<<<(N_NODES + 3) / 4, 256, 0, stream>>>(
        SbU, srt1, offs, bias, out);
}

// Round 10
// 312.977 us; speedup vs baseline: 1.2388x; 1.0887x over previous
//
#include <hip/hip_runtime.h>

#define N_NODES 100000
#define N_EDGES 3200000
#define D 128

#define K1C    391        // coarse buckets: bucket = dst >> 8 (256 nodes each)
#define CHUNK  4096       // edges per partition block (LDS 47 KB -> 3 blk/CU)
#define NCHUNK 782        // ceil(N_EDGES / CHUNK)
#define GEMMB  782        // gemm tiles (128 rows each) in the fused kernel
#define CAPB   8960       // arena capacity per bucket (mean 8192, +8.5 sigma)

// ---------------------------------------------------------------------------
// Workspace layout (bytes). ws >= 78,000,512 proven. Arena scheme: bucket b's
// records live at [b*CAPB, b*CAPB + cnt[b]) in both REC (int2) and SORT (uint)
// arenas — bases are arithmetic, so no global histogram/scan pass is needed.
// ---------------------------------------------------------------------------
static const size_t OFF_SB    = 0;           // S bf16 packed: N*64 uints = 25.6 MB
static const size_t OFF_REC   = 25600000;    // K1C*CAPB int2  = 28.03 MB
static const size_t OFF_SORT2 = 53626880;    // K1C*CAPB uint  = 14.01 MB
static const size_t OFF_OFFS  = 67640320;    // N ints
static const size_t OFF_GCUR  = 68040320;    // K1C ints (zeroed each launch)

typedef __attribute__((ext_vector_type(8))) short bf16x8;
typedef __attribute__((ext_vector_type(4))) float f32x4;

__device__ __forceinline__ unsigned short f2bf(float f) {
    unsigned u = __float_as_uint(f);
    return (unsigned short)((u + 0x7FFFu + ((u >> 16) & 1u)) >> 16);   // RNE
}

// ---------------------------------------------------------------------------
// LDS-staged coarse partition (verified R8/R9 internals), arena output:
// bucket base = b*CAPB + atomic cursor (cursors zero-initialized by memset).
// rec.x = src | (dst&255)<<17 ; rec.y = val bits.  Int atomics only.
// ---------------------------------------------------------------------------
__global__ __launch_bounds__(512) void partition_edges(
        const int* __restrict__ esrc,
        const int* __restrict__ edst,
        const float* __restrict__ eval,
        int* __restrict__ gcursor,
        int2* __restrict__ rec_out) {
    __shared__ int  hist[K1C];
    __shared__ int  lofs[K1C];
    __shared__ int  gbase[K1C];
    __shared__ int  cur[K1C];
    __shared__ int  wsum[8];
    __shared__ int2 staged[CHUNK];
    __shared__ unsigned short bkt[CHUNK];

    const int t    = threadIdx.x;
    const int lane = t & 63;
    const int wave = t >> 6;
    const int e0   = blockIdx.x * CHUNK;
    const int cnt  = min(CHUNK, N_EDGES - e0);

    for (int i = t; i < K1C; i += 512) hist[i] = 0;
    __syncthreads();

    // pass 1: block-local histogram (coalesced edst read; re-read is L2-hot)
    for (int i = t; i < cnt; i += 512)
        atomicAdd(&hist[edst[e0 + i] >> 8], 1);
    __syncthreads();

    // scan K1C entries: per-wave shfl_up inclusive scan + cross-wave combine
    int hv   = (t < K1C) ? hist[t] : 0;
    int incl = hv;
    for (int off = 1; off < 64; off <<= 1) {
        int u = __shfl_up(incl, off);
        if (lane >= off) incl += u;
    }
    if (lane == 63) wsum[wave] = incl;
    __syncthreads();
    {
        int pre = 0;
        for (int w = 0; w < wave; ++w) pre += wsum[w];
        if (t < K1C) {
            int excl = pre + incl - hv;
            lofs[t]  = excl;
            cur[t]   = excl;
            gbase[t] = hv ? (t * CAPB + atomicAdd(&gcursor[t], hv)) : 0;
        }
    }
    __syncthreads();

    // pass 2: re-read edges, scatter into LDS staging (bucket-sorted)
    for (int i = t; i < cnt; i += 512) {
        int e = e0 + i;
        int d = edst[e];
        int b = d >> 8;
        int pos = atomicAdd(&cur[b], 1);
        staged[pos] = make_int2(esrc[e] | ((d & 255) << 17), __float_as_int(eval[e]));
        bkt[pos] = (unsigned short)b;
    }
    __syncthreads();

    // writeout: contiguous per-bucket runs (~84 B each), coalesced from LDS
    for (int i = t; i < cnt; i += 512) {
        int bb = bkt[i];
        rec_out[gbase[bb] + (i - lofs[bb])] = staged[i];
    }
}

// ---------------------------------------------------------------------------
// FUSED kernel: blocks [0,GEMMB) run the verified MFMA gemm (S = X@W, 128-row
// tiles, verbatim); blocks [GEMMB, GEMMB+K1C) run fine_sort over one bucket
// arena (count from gcursor, base = c*CAPB). fine emits PACKED records:
// src(17b)|val-bf16(15b) (val>=0 -> sign bit free).
// ---------------------------------------------------------------------------
__global__ __launch_bounds__(256) void gemm_and_fine(
        const float* __restrict__ X,
        const float* __restrict__ W,
        unsigned* __restrict__ Sb,
        const int2* __restrict__ rec,
        const int* __restrict__ gcnt,
        int* __restrict__ offs,
        unsigned* __restrict__ sorted1) {
    __shared__ __align__(16) union {
        unsigned short wfrag[8][4][64][8];  // [ct][kt][lane][j] = 32 KB
        unsigned       stage[4][32][68];    // [wave][row][dword] = 34 KB
    } u;
    __shared__ int fh[256];
    __shared__ int fcur[256];
    __shared__ int fwsum[4];

    const int t    = threadIdx.x;
    const int lane = t & 63;
    const int wave = t >> 6;

    if (blockIdx.x < GEMMB) {
        // ----------------- gemm branch (verbatim R8 logic) -----------------
        const int quad = lane >> 4;
        const int li   = lane & 15;
        const int rowBase = blockIdx.x * 128;

        for (int i = t; i < D * D; i += 256) {
            int k = i >> 7, n = i & 127;
            u.wfrag[n >> 4][k >> 5][((k >> 3) & 3) * 16 + (n & 15)][k & 7] = f2bf(W[i]);
        }
        __syncthreads();

        f32x4 acc[2][8];
#pragma unroll
        for (int rt = 0; rt < 2; ++rt)
#pragma unroll
            for (int ct = 0; ct < 8; ++ct)
                acc[rt][ct] = (f32x4){0.f, 0.f, 0.f, 0.f};

#pragma unroll
        for (int kt = 0; kt < 4; ++kt) {
            bf16x8 a[2];
#pragma unroll
            for (int rt = 0; rt < 2; ++rt) {
                int row = rowBase + wave * 32 + rt * 16 + li;
                if (row >= N_NODES) row = N_NODES - 1;       // clamp; store masked
                const float* xp = X + (size_t)row * D + kt * 32 + quad * 8;
                float4 f0 = ((const float4*)xp)[0];
                float4 f1 = ((const float4*)xp)[1];
                bf16x8 av;
                av[0] = (short)f2bf(f0.x); av[1] = (short)f2bf(f0.y);
                av[2] = (short)f2bf(f0.z); av[3] = (short)f2bf(f0.w);
                av[4] = (short)f2bf(f1.x); av[5] = (short)f2bf(f1.y);
                av[6] = (short)f2bf(f1.z); av[7] = (short)f2bf(f1.w);
                a[rt] = av;
            }
#pragma unroll
            for (int ct = 0; ct < 8; ++ct) {
                bf16x8 b = *(const bf16x8*)&u.wfrag[ct][kt][lane][0];
                acc[0][ct] = __builtin_amdgcn_mfma_f32_16x16x32_bf16(a[0], b, acc[0][ct], 0, 0, 0);
                acc[1][ct] = __builtin_amdgcn_mfma_f32_16x16x32_bf16(a[1], b, acc[1][ct], 0, 0, 0);
            }
        }
        __syncthreads();

        unsigned short* sw = (unsigned short*)&u.stage[wave][0][0];  // 32 x 136 bf16
#pragma unroll
        for (int rt = 0; rt < 2; ++rt)
#pragma unroll
            for (int r = 0; r < 4; ++r) {
                int lrow = rt * 16 + quad * 4 + r;
#pragma unroll
                for (int ct = 0; ct < 8; ++ct)
                    sw[lrow * 136 + ct * 16 + li] = f2bf(acc[rt][ct][r]);
            }
        for (int lrow = 0; lrow < 32; ++lrow) {
            int node = rowBase + wave * 32 + lrow;
            if (node < N_NODES)
                Sb[(size_t)node * 64 + lane] = ((unsigned*)sw)[lrow * 68 + lane];
        }
    } else {
        // ----------------- fine_sort branch (256 threads) ------------------
        const int c    = blockIdx.x - GEMMB;
        const int beg  = c * CAPB;               // arena base
        const int bcnt = gcnt[c];                // records in this bucket
        const int end  = beg + bcnt;

        fh[t] = 0;
        __syncthreads();

        for (int i = beg + t; i < end; i += 256)
            atomicAdd(&fh[(rec[i].x >> 17) & 255], 1);
        __syncthreads();

        // inclusive scan of fh[0..255]: 4 waves x 64 entries + combine
        int hv   = fh[t];
        int incl = hv;
        for (int off = 1; off < 64; off <<= 1) {
            int uu = __shfl_up(incl, off);
            if (lane >= off) incl += uu;
        }
        if (lane == 63) fwsum[wave] = incl;
        __syncthreads();
        {
            int pre = 0;
            for (int w = 0; w < wave; ++w) pre += fwsum[w];
            int excl = pre + incl - hv;
            int node = c * 256 + t;
            if (node < N_NODES) offs[node] = beg + excl;
            fcur[t] = beg + excl;
        }
        __syncthreads();

        for (int i = beg + t; i < end; i += 256) {
            int2 q = rec[i];
            int dl = (q.x >> 17) & 255;
            int p = atomicAdd(&fcur[dl], 1);
            unsigned vb = f2bf(__int_as_float(q.y));          // val >= 0 -> bit15==0
            sorted1[p] = (unsigned)(q.x & 0x1FFFF) | ((vb & 0x7FFFu) << 17);
        }
    }
}

// ---------------------------------------------------------------------------
// Wave-per-node segmented reduce, QUARTER-wave record parallelism (verified
// R4/R9; at its measured floor: FETCH ~351 MB regardless of MLP/order).
// Arena-aware segment ends: within a bucket, end = offs[node+1]; for the
// bucket's LAST node, end = c*CAPB + cnt[c] (exact — arena gaps never read).
// Records are 4 B packed: src = p & 0x1FFFF, val = (p>>17)<<16 as f32 bits.
// Tail records zero-padded in-register (p=0 -> src 0, val +0.0) -> harmless.
// ---------------------------------------------------------------------------
#define FMA8(v, p) {                                                         \
    a0 += (v) * __uint_as_float((p).x << 16);                                \
    a1 += (v) * __uint_as_float((p).x & 0xFFFF0000u);                        \
    a2 += (v) * __uint_as_float((p).y << 16);                                \
    a3 += (v) * __uint_as_float((p).y & 0xFFFF0000u);                        \
    a4 += (v) * __uint_as_float((p).z << 16);                                \
    a5 += (v) * __uint_as_float((p).z & 0xFFFF0000u);                        \
    a6 += (v) * __uint_as_float((p).w << 16);                                \
    a7 += (v) * __uint_as_float((p).w & 0xFFFF0000u);                        \
}

__global__ __launch_bounds__(256) void reduce_segments(
        const unsigned* __restrict__ Sb,
        const unsigned* __restrict__ sorted,
        const int* __restrict__ offs,
        const int* __restrict__ gcnt,
        const float* __restrict__ bias,
        float* __restrict__ out) {
    const int lane = threadIdx.x & 63;
    const int node = (blockIdx.x * 256 + threadIdx.x) >> 6;
    if (node >= N_NODES) return;

    const int qr = lane >> 4;        // which record of the group of 4
    const int ql = lane & 15;        // lane within quarter: feats 8ql..8ql+7

    const int beg = offs[node];
    const bool blast = ((node & 255) == 255) || (node == N_NODES - 1);
    const int end = blast ? ((node >> 8) * CAPB + gcnt[node >> 8])
                          : offs[node + 1];

    float a0 = 0.f, a1 = 0.f, a2 = 0.f, a3 = 0.f;
    float a4 = 0.f, a5 = 0.f, a6 = 0.f, a7 = 0.f;

    for (int base = beg; base < end; base += 64) {
        const int m = min(64, end - base);
        unsigned rec = 0;
        if (base + lane < end) rec = sorted[base + lane];
        const int ng = (m + 3) >> 2;         // groups of 4 records

        int g = 0;
        for (; g + 4 <= ng; g += 4) {
            int i0 = 4 * (g + 0) + qr, i1 = 4 * (g + 1) + qr;
            int i2 = 4 * (g + 2) + qr, i3 = 4 * (g + 3) + qr;
            unsigned r0 = (unsigned)__shfl((int)rec, i0);
            unsigned r1 = (unsigned)__shfl((int)rec, i1);
            unsigned r2 = (unsigned)__shfl((int)rec, i2);
            unsigned r3 = (unsigned)__shfl((int)rec, i3);
            int s0 = r0 & 0x1FFFF, s1 = r1 & 0x1FFFF;
            int s2 = r2 & 0x1FFFF, s3 = r3 & 0x1FFFF;
            float v0 = __uint_as_float((r0 >> 17) << 16);
            float v1 = __uint_as_float((r1 >> 17) << 16);
            float v2 = __uint_as_float((r2 >> 17) << 16);
            float v3 = __uint_as_float((r3 >> 17) << 16);
            uint4 p0 = ((const uint4*)(Sb + (size_t)s0 * 64))[ql];
            uint4 p1 = ((const uint4*)(Sb + (size_t)s1 * 64))[ql];
            uint4 p2 = ((const uint4*)(Sb + (size_t)s2 * 64))[ql];
            uint4 p3 = ((const uint4*)(Sb + (size_t)s3 * 64))[ql];
            FMA8(v0, p0);
            FMA8(v1, p1);
            FMA8(v2, p2);
            FMA8(v3, p3);
        }
        for (; g < ng; ++g) {
            int i0 = 4 * g + qr;
            unsigned r0 = (unsigned)__shfl((int)rec, i0);
            int s0 = r0 & 0x1FFFF;
            float v0 = __uint_as_float((r0 >> 17) << 16);
            uint4 p0 = ((const uint4*)(Sb + (size_t)s0 * 64))[ql];
            FMA8(v0, p0);
        }
    }

    // combine the four quarters (feats 8ql..8ql+7 live in lanes ql, ql+16,
    // ql+32, ql+48)
    a0 += __shfl(a0, lane ^ 16); a1 += __shfl(a1, lane ^ 16);
    a2 += __shfl(a2, lane ^ 16); a3 += __shfl(a3, lane ^ 16);
    a4 += __shfl(a4, lane ^ 16); a5 += __shfl(a5, lane ^ 16);
    a6 += __shfl(a6, lane ^ 16); a7 += __shfl(a7, lane ^ 16);
    a0 += __shfl(a0, lane ^ 32); a1 += __shfl(a1, lane ^ 32);
    a2 += __shfl(a2, lane ^ 32); a3 += __shfl(a3, lane ^ 32);
    a4 += __shfl(a4, lane ^ 32); a5 += __shfl(a5, lane ^ 32);
    a6 += __shfl(a6, lane ^ 32); a7 += __shfl(a7, lane ^ 32);

    if (qr == 0) {
        float4 b0 = ((const float4*)bias)[2 * ql];
        float4 b1 = ((const float4*)bias)[2 * ql + 1];
        float4 r0 = make_float4(a0 + b0.x, a1 + b0.y, a2 + b0.z, a3 + b0.w);
        float4 r1 = make_float4(a4 + b1.x, a5 + b1.y, a6 + b1.z, a7 + b1.w);
        ((float4*)(out + (size_t)node * D))[2 * ql]     = r0;
        ((float4*)(out + (size_t)node * D))[2 * ql + 1] = r1;
    }
}

extern "C" void kernel_launch(void* const* d_in, const int* in_sizes, int n_in,
                              void* d_out, int out_size, void* d_ws, size_t ws_size,
                              hipStream_t stream) {
    const float* X    = (const float*)d_in[0];
    const int*   esrc = (const int*)  d_in[1];
    const int*   edst = (const int*)  d_in[2];
    const float* eval = (const float*)d_in[3];
    const float* W    = (const float*)d_in[4];
    const float* bias = (const float*)d_in[5];
    float* out = (float*)d_out;

    char* ws = (char*)d_ws;
    unsigned* SbU   = (unsigned*)(ws + OFF_SB);
    int2*     recs  = (int2*)    (ws + OFF_REC);
    unsigned* srt1  = (unsigned*)(ws + OFF_SORT2);
    int*      offs  = (int*)     (ws + OFF_OFFS);
    int*      gcur  = (int*)     (ws + OFF_GCUR);

    // Zero per-bucket arena cursors (bucket bases are arithmetic: b*CAPB)
    hipMemsetAsync(gcur, 0, K1C * 4, stream);

    // Coarse partition into bucket arenas (no histogram/scan pass needed)
    partition_edges<<<NCHUNK, 512, 0, stream>>>(esrc, edst, eval, gcur, recs);

    // Fused: gemm (blocks 0..781) || fine_sort per bucket (blocks 782..1172)
    gemm_and_fine<<<GEMMB + K1C, 256, 0, stream>>>(
        X, W, SbU, recs, gcur, offs, srt1);

    // Segmented reduce: out[n] = bias + sum val * S[src]
    reduce_segments<<<(N_NODES + 3) / 4, 256, 0, stream>>>(
        SbU, srt1, offs, gcur, bias, out);
}